// Round 2
// baseline (2142.241 us; speedup 1.0000x reference)
//
#include <hip/hip_runtime.h>

// DNAMite GAM on MI355X. Round 1: MFMA f16 (16x16x32), weights held in
// per-wave register B-fragments (loaded once per block), activations staged
// in LDS as f16 with XOR-swizzled 16B blocks (conflict-free ds_read_b128).

typedef _Float16 f16x8 __attribute__((ext_vector_type(8)));
typedef float f32x4 __attribute__((ext_vector_type(4)));

constexpr int Bsz   = 512;
constexpr int NF    = 64;
constexpr int NE    = 32;
constexpr int NH    = 128;
constexpr int NP    = 2016;
constexpr int NBLK  = NP + NF;   // 2080
constexpr int BT    = 64;        // batch tile
constexpr int NTILE = Bsz / BT;  // 8
constexpr int NCH   = 32;        // ws accumulation chunks

__device__ __forceinline__ float smoothz(float z) {
  float s = fmaf(-2.0f * z * z, z, fmaf(1.5f, z, 0.5f));
  if (z <= -0.5f) s = 0.0f;
  if (z >=  0.5f) s = 1.0f;
  return s;
}

__global__ void zero_ws_kernel(float* __restrict__ ws) {
  ws[blockIdx.x * 256 + threadIdx.x] = 0.0f;
}

__global__ __launch_bounds__(256, 3) void fused_groups_kernel(
    const int* __restrict__ mains, const int* __restrict__ pairs,
    const float* __restrict__ emb,
    const float* __restrict__ mw0, const float* __restrict__ mw1,
    const float* __restrict__ mw2, const float* __restrict__ mb0,
    const float* __restrict__ mb1, const float* __restrict__ mb2,
    const float* __restrict__ z_main,
    const float* __restrict__ pw0, const float* __restrict__ pw1,
    const float* __restrict__ pw2, const float* __restrict__ pb0,
    const float* __restrict__ pb1, const float* __restrict__ pb2,
    const float* __restrict__ z_pairs,
    const int* __restrict__ pairs_list, const int* __restrict__ foff,
    float* __restrict__ ws) {
  // f16 activation tiles, XOR-swizzled 16B blocks: element (row, k) lives at
  // [row*K + ((k>>3)^(row&7))*8 + (k&7)]  -> ds_read_b128 A-frags, 2-way max.
  __shared__ _Float16 sA[BT * 64];    // layer-0 input, K=64 (mains use 32)
  __shared__ _Float16 sH[BT * NH];    // layer-1 input (H1), K=128

  const int t    = threadIdx.x;
  const int wave = t >> 6;
  const int lane = t & 63;
  const int l    = lane & 15;   // MFMA 16-index (A row / B col / D col)
  const int qd   = lane >> 4;   // MFMA quad (k-subchunk / D row group)
  const int wnb  = wave * 32;   // this wave's n-base (2 chunks of 16)
  const int g    = blockIdx.x;
  const bool is_pair = (g < NP);

  const float *W0, *W1, *w2p, *bv0, *bv1;
  float b2s, z;
  int kc0, off0 = 0, off1 = 0, fid = 0;
  if (is_pair) {
    W0  = pw0 + (size_t)g * (2 * NE * NH);
    W1  = pw1 + (size_t)g * (NH * NH);
    w2p = pw2 + (size_t)g * NH;
    bv0 = pb0 + (size_t)g * NH;
    bv1 = pb1 + (size_t)g * NH;
    b2s = pb2[g];
    z   = smoothz(z_pairs[g]);
    kc0 = 2;  // K0 = 64
    off0 = foff[pairs_list[2 * g + 0]];
    off1 = foff[pairs_list[2 * g + 1]];
  } else {
    fid = g - NP;
    W0  = mw0 + (size_t)fid * (NE * NH);
    W1  = mw1 + (size_t)fid * (NH * NH);
    w2p = mw2 + (size_t)fid * NH;
    bv0 = mb0 + (size_t)fid * NH;
    bv1 = mb1 + (size_t)fid * NH;
    b2s = mb2[fid];
    z   = smoothz(z_main[fid]);
    kc0 = 1;  // K0 = 32
    off0 = foff[fid];
  }

  // Per-lane scalars: bias / w2 for this lane's two output columns.
  float b0v[2], b1v[2], wv2[2];
#pragma unroll
  for (int nc = 0; nc < 2; ++nc) {
    const int col = wnb + nc * 16 + l;
    b0v[nc] = bv0[col];
    b1v[nc] = bv1[col];
    wv2[nc] = w2p[col];
  }

  // B-fragments (weights), loaded ONCE per block, kept in VGPRs.
  // Lane holds B[k = kc*32 + qd*8 + j][n = wnb + nc*16 + l], j=0..7.
  f16x8 bf0[2][2], bf1[2][4];
#pragma unroll
  for (int nc = 0; nc < 2; ++nc)
    for (int kc = 0; kc < 2; ++kc) {
      if (kc < kc0) {
        const float* p = W0 + (size_t)(kc * 32 + qd * 8) * NH + wnb + nc * 16 + l;
        f16x8 v;
#pragma unroll
        for (int j = 0; j < 8; ++j) v[j] = (_Float16)p[j * NH];
        bf0[nc][kc] = v;
      }
    }
#pragma unroll
  for (int nc = 0; nc < 2; ++nc)
#pragma unroll
    for (int kc = 0; kc < 4; ++kc) {
      const float* p = W1 + (size_t)(kc * 32 + qd * 8) * NH + wnb + nc * 16 + l;
      f16x8 v;
#pragma unroll
      for (int j = 0; j < 8; ++j) v[j] = (_Float16)p[j * NH];
      bf1[nc][kc] = v;
    }

  for (int tile = 0; tile < NTILE; ++tile) {
    const int bbase = tile * BT;
    __syncthreads();  // prior tile's sA/sH reads complete before overwrite

    // ---- stage layer-0 input into sA (f16, swizzled) ----
    {
      const int row = t & 63;
      const int q   = t >> 6;
      const int b   = bbase + row;
      if (is_pair) {
        const int which = q >> 1;
        const int bin = pairs[b * (NP * 2) + 2 * g + which];
        const int idx = bin + (which ? off1 : off0);
        const float* er = emb + (size_t)idx * NE + (q & 1) * 16;
        const float4 e0 = ((const float4*)er)[0];
        const float4 e1 = ((const float4*)er)[1];
        const float4 e2 = ((const float4*)er)[2];
        const float4 e3 = ((const float4*)er)[3];
        f16x8 h0, h1;
        h0[0] = (_Float16)e0.x; h0[1] = (_Float16)e0.y;
        h0[2] = (_Float16)e0.z; h0[3] = (_Float16)e0.w;
        h0[4] = (_Float16)e1.x; h0[5] = (_Float16)e1.y;
        h0[6] = (_Float16)e1.z; h0[7] = (_Float16)e1.w;
        h1[0] = (_Float16)e2.x; h1[1] = (_Float16)e2.y;
        h1[2] = (_Float16)e2.z; h1[3] = (_Float16)e2.w;
        h1[4] = (_Float16)e3.x; h1[5] = (_Float16)e3.y;
        h1[6] = (_Float16)e3.z; h1[7] = (_Float16)e3.w;
        const int blk0 = (2 * q)     ^ (row & 7);
        const int blk1 = (2 * q + 1) ^ (row & 7);
        *(f16x8*)&sA[row * 64 + blk0 * 8] = h0;
        *(f16x8*)&sA[row * 64 + blk1 * 8] = h1;
      } else {
        const int bin = mains[b * NF + fid];
        const int idx = bin + off0;
        const float* er = emb + (size_t)idx * NE + q * 8;
        const float4 e0 = ((const float4*)er)[0];
        const float4 e1 = ((const float4*)er)[1];
        f16x8 h0;
        h0[0] = (_Float16)e0.x; h0[1] = (_Float16)e0.y;
        h0[2] = (_Float16)e0.z; h0[3] = (_Float16)e0.w;
        h0[4] = (_Float16)e1.x; h0[5] = (_Float16)e1.y;
        h0[6] = (_Float16)e1.z; h0[7] = (_Float16)e1.w;
        const int blk = q ^ (row & 7);
        *(f16x8*)&sA[row * 64 + blk * 8] = h0;
      }
    }
    __syncthreads();

    // ---- GEMM0: H1 = relu(E*W0 + b0), MFMA 16x16x32 ----
    f32x4 acc0[4][2];
#pragma unroll
    for (int m = 0; m < 4; ++m)
#pragma unroll
      for (int nc = 0; nc < 2; ++nc)
        acc0[m][nc] = (f32x4){b0v[nc], b0v[nc], b0v[nc], b0v[nc]};

#pragma unroll
    for (int m = 0; m < 4; ++m) {
      const int brow = m * 16 + l;
      for (int kc = 0; kc < kc0; ++kc) {
        const f16x8 af =
            *(const f16x8*)&sA[brow * 64 + (((kc * 4 + qd) ^ (l & 7)) * 8)];
#pragma unroll
        for (int nc = 0; nc < 2; ++nc)
          acc0[m][nc] = __builtin_amdgcn_mfma_f32_16x16x32_f16(
              af, bf0[nc][kc], acc0[m][nc], 0, 0, 0);
      }
    }

    // ---- relu + write H1 to sH (f16, swizzled); D-layout: row=qd*4+r, col=l
#pragma unroll
    for (int m = 0; m < 4; ++m)
#pragma unroll
      for (int nc = 0; nc < 2; ++nc)
#pragma unroll
        for (int r = 0; r < 4; ++r) {
          const float v = fmaxf(acc0[m][nc][r], 0.0f);
          const int row = m * 16 + qd * 4 + r;
          const int col = wnb + nc * 16 + l;
          sH[row * NH + (((col >> 3) ^ (row & 7)) * 8) + (col & 7)] =
              (_Float16)v;
        }
    __syncthreads();

    // ---- GEMM1: H2 = relu(H1*W1 + b1) ----
    f32x4 acc1[4][2];
#pragma unroll
    for (int m = 0; m < 4; ++m)
#pragma unroll
      for (int nc = 0; nc < 2; ++nc)
        acc1[m][nc] = (f32x4){b1v[nc], b1v[nc], b1v[nc], b1v[nc]};

#pragma unroll
    for (int m = 0; m < 4; ++m) {
      const int brow = m * 16 + l;
#pragma unroll
      for (int kc = 0; kc < 4; ++kc) {
        const f16x8 af =
            *(const f16x8*)&sH[brow * NH + (((kc * 4 + qd) ^ (l & 7)) * 8)];
#pragma unroll
        for (int nc = 0; nc < 2; ++nc)
          acc1[m][nc] = __builtin_amdgcn_mfma_f32_16x16x32_f16(
              af, bf1[nc][kc], acc1[m][nc], 0, 0, 0);
      }
    }

    // ---- layer 2: y[b] += relu(H2) . w2 over this wave's 32 cols ----
    float v16[16];
#pragma unroll
    for (int m = 0; m < 4; ++m)
#pragma unroll
      for (int r = 0; r < 4; ++r)
        v16[m * 4 + r] = fmaf(fmaxf(acc1[m][0][r], 0.0f), wv2[0],
                              fmaxf(acc1[m][1][r], 0.0f) * wv2[1]);

    // tree exchange: after step s, lane holds sums for idxs whose low s+1
    // bits match the lane's; final: lane l holds idx = l (m = l>>2, r = l&3).
    const int lb0 = l & 1, lb1 = (l >> 1) & 1, lb2 = (l >> 2) & 1,
              lb3 = (l >> 3) & 1;
    float v8[8];
#pragma unroll
    for (int i = 0; i < 8; ++i) {
      const float mine   = lb0 ? v16[2 * i + 1] : v16[2 * i];
      const float theirs = lb0 ? v16[2 * i]     : v16[2 * i + 1];
      v8[i] = mine + __shfl_xor(theirs, 1, 64);
    }
    float v4[4];
#pragma unroll
    for (int i = 0; i < 4; ++i) {
      const float mine   = lb1 ? v8[2 * i + 1] : v8[2 * i];
      const float theirs = lb1 ? v8[2 * i]     : v8[2 * i + 1];
      v4[i] = mine + __shfl_xor(theirs, 2, 64);
    }
    float v2[2];
#pragma unroll
    for (int i = 0; i < 2; ++i) {
      const float mine   = lb2 ? v4[2 * i + 1] : v4[2 * i];
      const float theirs = lb2 ? v4[2 * i]     : v4[2 * i + 1];
      v2[i] = mine + __shfl_xor(theirs, 4, 64);
    }
    const float mine1   = lb3 ? v2[1] : v2[0];
    const float theirs1 = lb3 ? v2[0] : v2[1];
    float v1 = mine1 + __shfl_xor(theirs1, 8, 64);

    const int m_o = l >> 2;
    const int r_o = l & 3;
    const int row_local = m_o * 16 + qd * 4 + r_o;
    float val = v1;
    if (wave == 0) val += b2s;  // b2 added exactly once per (g, b)
    val *= z;
    atomicAdd(&ws[(g & (NCH - 1)) * Bsz + bbase + row_local], val);
  }
}

__global__ void reduce_ws_kernel(const float* __restrict__ ws,
                                 float* __restrict__ out) {
  const int b = blockIdx.x * 256 + threadIdx.x;
  float s = 0.0f;
#pragma unroll
  for (int c = 0; c < NCH; ++c) s += ws[c * Bsz + b];
  out[b] = s;
}

extern "C" void kernel_launch(void* const* d_in, const int* in_sizes, int n_in,
                              void* d_out, int out_size, void* d_ws,
                              size_t ws_size, hipStream_t stream) {
  const int*   mains      = (const int*)d_in[0];
  const int*   pairs      = (const int*)d_in[1];
  const float* emb        = (const float*)d_in[2];
  const float* mw0        = (const float*)d_in[3];
  const float* mw1        = (const float*)d_in[4];
  const float* mw2        = (const float*)d_in[5];
  const float* mb0        = (const float*)d_in[6];
  const float* mb1        = (const float*)d_in[7];
  const float* mb2        = (const float*)d_in[8];
  const float* z_main     = (const float*)d_in[9];
  const float* pw0        = (const float*)d_in[10];
  const float* pw1        = (const float*)d_in[11];
  const float* pw2        = (const float*)d_in[12];
  const float* pb0        = (const float*)d_in[13];
  const float* pb1        = (const float*)d_in[14];
  const float* pb2        = (const float*)d_in[15];
  const float* z_pairs    = (const float*)d_in[16];
  const int*   pairs_list = (const int*)d_in[17];
  const int*   foff       = (const int*)d_in[18];
  float* ws  = (float*)d_ws;
  float* out = (float*)d_out;

  zero_ws_kernel<<<(NCH * Bsz) / 256, 256, 0, stream>>>(ws);
  fused_groups_kernel<<<NBLK, 256, 0, stream>>>(
      mains, pairs, emb, mw0, mw1, mw2, mb0, mb1, mb2, z_main, pw0, pw1, pw2,
      pb0, pb1, pb2, z_pairs, pairs_list, foff, ws);
  reduce_ws_kernel<<<Bsz / 256, 256, 0, stream>>>(ws, out);
}

// Round 3
// 2084.179 us; speedup vs baseline: 1.0279x; 1.0279x over previous
//
#include <hip/hip_runtime.h>

// DNAMite GAM on MI355X. Round 2: same verified MFMA f16 math as round 1, but
// latency-restructured: no global atomics (private ws slice per group + tree
// reduce), 2 tiles/block (grid 8320), pairs pre-transposed for coalescing.

typedef _Float16 f16x8 __attribute__((ext_vector_type(8)));
typedef float f32x4 __attribute__((ext_vector_type(4)));

constexpr int Bsz = 512;
constexpr int NF  = 64;
constexpr int NE  = 32;
constexpr int NH  = 128;
constexpr int NP  = 2016;
constexpr int NG  = NP + NF;       // 2080 groups
constexpr int BT  = 64;            // batch tile
constexpr int TPB = 2;             // tiles per block
constexpr int BPG = (Bsz / BT) / TPB;  // 4 blocks per group
constexpr int NSEG = 8, GSEG = NG / NSEG;  // 260

// ws layout (floats): [NG*Bsz] partials | [NSEG*Bsz] stage2 | pairsT ints
constexpr size_t WS_S2 = (size_t)NG * Bsz;
constexpr size_t WS_PT = WS_S2 + (size_t)NSEG * Bsz;
// total: (1064960 + 4096)*4 B + 4032*512*4 B ~= 12.5 MB of ws

__device__ __forceinline__ float smoothz(float z) {
  float s = fmaf(-2.0f * z * z, z, fmaf(1.5f, z, 0.5f));
  if (z <= -0.5f) s = 0.0f;
  if (z >=  0.5f) s = 1.0f;
  return s;
}

// [512][4032] -> [4032][512] int transpose, LDS-tiled 32x32.
__global__ void transpose_pairs_kernel(const int* __restrict__ pairs,
                                       int* __restrict__ pt) {
  __shared__ int tile[32][33];
  const int bt = blockIdx.x;   // 16 b-tiles
  const int qt = blockIdx.y;   // 126 q-tiles
  const int t  = threadIdx.x;
  const int tq = t & 7, tb = t >> 3;
  const int brow  = bt * 32 + tb;
  const int qbase = qt * 32 + tq * 4;
#pragma unroll
  for (int j = 0; j < 4; ++j)
    tile[tb][tq * 4 + j] = pairs[brow * (2 * NP) + qbase + j];
  __syncthreads();
  const int ob = t & 7, oq = t >> 3;
  const int qrow = qt * 32 + oq;
#pragma unroll
  for (int j = 0; j < 4; ++j)
    pt[(size_t)qrow * Bsz + bt * 32 + ob * 4 + j] = tile[ob * 4 + j][oq];
}

__global__ __launch_bounds__(256, 4) void fused_groups_kernel(
    const int* __restrict__ mains, const int* __restrict__ pt,
    const float* __restrict__ emb,
    const float* __restrict__ mw0, const float* __restrict__ mw1,
    const float* __restrict__ mw2, const float* __restrict__ mb0,
    const float* __restrict__ mb1, const float* __restrict__ mb2,
    const float* __restrict__ z_main,
    const float* __restrict__ pw0, const float* __restrict__ pw1,
    const float* __restrict__ pw2, const float* __restrict__ pb0,
    const float* __restrict__ pb1, const float* __restrict__ pb2,
    const float* __restrict__ z_pairs,
    const int* __restrict__ pairs_list, const int* __restrict__ foff,
    float* __restrict__ ws) {
  // f16 activation tiles, XOR-swizzled 16B blocks (verified round 1):
  // element (row, k) -> [row*K + ((k>>3)^(row&7))*8 + (k&7)]
  __shared__ _Float16 sA[BT * 64];
  __shared__ _Float16 sH[BT * NH];
  __shared__ float    sRed[4 * BT];

  const int t    = threadIdx.x;
  const int wave = t >> 6;
  const int lane = t & 63;
  const int l    = lane & 15;
  const int qd   = lane >> 4;
  const int wnb  = wave * 32;
  const int g    = blockIdx.x >> 2;       // consecutive blocks share a group
  const int tp   = blockIdx.x & (BPG - 1);
  const bool is_pair = (g < NP);

  const float *W0, *W1, *w2p, *bv0, *bv1;
  float b2s, z;
  int kc0, off0 = 0, off1 = 0, fid = 0;
  if (is_pair) {
    W0  = pw0 + (size_t)g * (2 * NE * NH);
    W1  = pw1 + (size_t)g * (NH * NH);
    w2p = pw2 + (size_t)g * NH;
    bv0 = pb0 + (size_t)g * NH;
    bv1 = pb1 + (size_t)g * NH;
    b2s = pb2[g];
    z   = smoothz(z_pairs[g]);
    kc0 = 2;
    off0 = foff[pairs_list[2 * g + 0]];
    off1 = foff[pairs_list[2 * g + 1]];
  } else {
    fid = g - NP;
    W0  = mw0 + (size_t)fid * (NE * NH);
    W1  = mw1 + (size_t)fid * (NH * NH);
    w2p = mw2 + (size_t)fid * NH;
    bv0 = mb0 + (size_t)fid * NH;
    bv1 = mb1 + (size_t)fid * NH;
    b2s = mb2[fid];
    z   = smoothz(z_main[fid]);
    kc0 = 1;
    off0 = foff[fid];
  }

  float b0v[2], b1v[2], wv2[2];
#pragma unroll
  for (int nc = 0; nc < 2; ++nc) {
    const int col = wnb + nc * 16 + l;
    b0v[nc] = bv0[col];
    b1v[nc] = bv1[col];
    wv2[nc] = w2p[col];
  }

  // B-fragments (weights) in VGPRs, loaded once per block.
  // Lane holds B[k = kc*32 + qd*8 + j][n = wnb + nc*16 + l].
  f16x8 bf0[2][2], bf1[2][4];
#pragma unroll
  for (int nc = 0; nc < 2; ++nc)
    for (int kc = 0; kc < 2; ++kc) {
      if (kc < kc0) {
        const float* p = W0 + (size_t)(kc * 32 + qd * 8) * NH + wnb + nc * 16 + l;
        f16x8 v;
#pragma unroll
        for (int j = 0; j < 8; ++j) v[j] = (_Float16)p[j * NH];
        bf0[nc][kc] = v;
      }
    }
#pragma unroll
  for (int nc = 0; nc < 2; ++nc)
#pragma unroll
    for (int kc = 0; kc < 4; ++kc) {
      const float* p = W1 + (size_t)(kc * 32 + qd * 8) * NH + wnb + nc * 16 + l;
      f16x8 v;
#pragma unroll
      for (int j = 0; j < 8; ++j) v[j] = (_Float16)p[j * NH];
      bf1[nc][kc] = v;
    }

  for (int tt = 0; tt < TPB; ++tt) {
    const int tile  = tp * TPB + tt;
    const int bbase = tile * BT;
    __syncthreads();

    // ---- stage layer-0 input into sA (f16, swizzled) ----
    {
      const int row = t & 63;
      const int q   = t >> 6;
      const int b   = bbase + row;
      if (is_pair) {
        const int which = q >> 1;
        const int bin = pt[(size_t)(2 * g + which) * Bsz + b];  // coalesced
        const int idx = bin + (which ? off1 : off0);
        const float* er = emb + (size_t)idx * NE + (q & 1) * 16;
        const float4 e0 = ((const float4*)er)[0];
        const float4 e1 = ((const float4*)er)[1];
        const float4 e2 = ((const float4*)er)[2];
        const float4 e3 = ((const float4*)er)[3];
        f16x8 h0, h1;
        h0[0] = (_Float16)e0.x; h0[1] = (_Float16)e0.y;
        h0[2] = (_Float16)e0.z; h0[3] = (_Float16)e0.w;
        h0[4] = (_Float16)e1.x; h0[5] = (_Float16)e1.y;
        h0[6] = (_Float16)e1.z; h0[7] = (_Float16)e1.w;
        h1[0] = (_Float16)e2.x; h1[1] = (_Float16)e2.y;
        h1[2] = (_Float16)e2.z; h1[3] = (_Float16)e2.w;
        h1[4] = (_Float16)e3.x; h1[5] = (_Float16)e3.y;
        h1[6] = (_Float16)e3.z; h1[7] = (_Float16)e3.w;
        const int blk0 = (2 * q)     ^ (row & 7);
        const int blk1 = (2 * q + 1) ^ (row & 7);
        *(f16x8*)&sA[row * 64 + blk0 * 8] = h0;
        *(f16x8*)&sA[row * 64 + blk1 * 8] = h1;
      } else {
        const int bin = mains[b * NF + fid];
        const int idx = bin + off0;
        const float* er = emb + (size_t)idx * NE + q * 8;
        const float4 e0 = ((const float4*)er)[0];
        const float4 e1 = ((const float4*)er)[1];
        f16x8 h0;
        h0[0] = (_Float16)e0.x; h0[1] = (_Float16)e0.y;
        h0[2] = (_Float16)e0.z; h0[3] = (_Float16)e0.w;
        h0[4] = (_Float16)e1.x; h0[5] = (_Float16)e1.y;
        h0[6] = (_Float16)e1.z; h0[7] = (_Float16)e1.w;
        const int blk = q ^ (row & 7);
        *(f16x8*)&sA[row * 64 + blk * 8] = h0;
      }
    }
    __syncthreads();

    // ---- GEMM0: H1 = relu(E*W0 + b0) ----
    f32x4 acc0[4][2];
#pragma unroll
    for (int m = 0; m < 4; ++m)
#pragma unroll
      for (int nc = 0; nc < 2; ++nc)
        acc0[m][nc] = (f32x4){b0v[nc], b0v[nc], b0v[nc], b0v[nc]};

#pragma unroll
    for (int m = 0; m < 4; ++m) {
      const int brow = m * 16 + l;
      for (int kc = 0; kc < kc0; ++kc) {
        const f16x8 af =
            *(const f16x8*)&sA[brow * 64 + (((kc * 4 + qd) ^ (l & 7)) * 8)];
#pragma unroll
        for (int nc = 0; nc < 2; ++nc)
          acc0[m][nc] = __builtin_amdgcn_mfma_f32_16x16x32_f16(
              af, bf0[nc][kc], acc0[m][nc], 0, 0, 0);
      }
    }

    // ---- relu + write H1 to sH (f16, swizzled); D: row=qd*4+r, col=l ----
#pragma unroll
    for (int m = 0; m < 4; ++m)
#pragma unroll
      for (int nc = 0; nc < 2; ++nc)
#pragma unroll
        for (int r = 0; r < 4; ++r) {
          const float v = fmaxf(acc0[m][nc][r], 0.0f);
          const int row = m * 16 + qd * 4 + r;
          const int col = wnb + nc * 16 + l;
          sH[row * NH + (((col >> 3) ^ (row & 7)) * 8) + (col & 7)] =
              (_Float16)v;
        }
    __syncthreads();

    // ---- GEMM1: H2 = relu(H1*W1 + b1) ----
    f32x4 acc1[4][2];
#pragma unroll
    for (int m = 0; m < 4; ++m)
#pragma unroll
      for (int nc = 0; nc < 2; ++nc)
        acc1[m][nc] = (f32x4){b1v[nc], b1v[nc], b1v[nc], b1v[nc]};

#pragma unroll
    for (int m = 0; m < 4; ++m) {
      const int brow = m * 16 + l;
#pragma unroll
      for (int kc = 0; kc < 4; ++kc) {
        const f16x8 af =
            *(const f16x8*)&sH[brow * NH + (((kc * 4 + qd) ^ (l & 7)) * 8)];
#pragma unroll
        for (int nc = 0; nc < 2; ++nc)
          acc1[m][nc] = __builtin_amdgcn_mfma_f32_16x16x32_f16(
              af, bf1[nc][kc], acc1[m][nc], 0, 0, 0);
      }
    }

    // ---- layer 2: per-wave partial y over its 32 cols ----
    float v16[16];
#pragma unroll
    for (int m = 0; m < 4; ++m)
#pragma unroll
      for (int r = 0; r < 4; ++r)
        v16[m * 4 + r] = fmaf(fmaxf(acc1[m][0][r], 0.0f), wv2[0],
                              fmaxf(acc1[m][1][r], 0.0f) * wv2[1]);

    const int lb0 = l & 1, lb1 = (l >> 1) & 1, lb2 = (l >> 2) & 1,
              lb3 = (l >> 3) & 1;
    float v8[8];
#pragma unroll
    for (int i = 0; i < 8; ++i) {
      const float mine   = lb0 ? v16[2 * i + 1] : v16[2 * i];
      const float theirs = lb0 ? v16[2 * i]     : v16[2 * i + 1];
      v8[i] = mine + __shfl_xor(theirs, 1, 64);
    }
    float v4[4];
#pragma unroll
    for (int i = 0; i < 4; ++i) {
      const float mine   = lb1 ? v8[2 * i + 1] : v8[2 * i];
      const float theirs = lb1 ? v8[2 * i]     : v8[2 * i + 1];
      v4[i] = mine + __shfl_xor(theirs, 2, 64);
    }
    float v2[2];
#pragma unroll
    for (int i = 0; i < 2; ++i) {
      const float mine   = lb2 ? v4[2 * i + 1] : v4[2 * i];
      const float theirs = lb2 ? v4[2 * i]     : v4[2 * i + 1];
      v2[i] = mine + __shfl_xor(theirs, 4, 64);
    }
    const float mine1   = lb3 ? v2[1] : v2[0];
    const float theirs1 = lb3 ? v2[0] : v2[1];
    const float v1 = mine1 + __shfl_xor(theirs1, 8, 64);

    // cross-wave reduce through LDS, then ONE write per (g, b) — no atomics
    const int row_local = (l >> 2) * 16 + qd * 4 + (l & 3);
    sRed[wave * BT + row_local] = v1;
    __syncthreads();
    if (t < BT) {
      const float s =
          sRed[t] + sRed[BT + t] + sRed[2 * BT + t] + sRed[3 * BT + t];
      ws[(size_t)g * Bsz + bbase + t] = (s + b2s) * z;
    }
  }
}

__global__ void reduce1_kernel(const float* __restrict__ part,
                               float* __restrict__ s2) {
  const int b   = blockIdx.x * 256 + threadIdx.x;
  const int seg = blockIdx.y;
  float s = 0.0f;
#pragma unroll 8
  for (int g = seg * GSEG; g < (seg + 1) * GSEG; ++g)
    s += part[(size_t)g * Bsz + b];
  s2[seg * Bsz + b] = s;
}

__global__ void reduce2_kernel(const float* __restrict__ s2,
                               float* __restrict__ out) {
  const int b = blockIdx.x * 256 + threadIdx.x;
  float s = 0.0f;
#pragma unroll
  for (int k = 0; k < NSEG; ++k) s += s2[k * Bsz + b];
  out[b] = s;
}

extern "C" void kernel_launch(void* const* d_in, const int* in_sizes, int n_in,
                              void* d_out, int out_size, void* d_ws,
                              size_t ws_size, hipStream_t stream) {
  const int*   mains      = (const int*)d_in[0];
  const int*   pairs      = (const int*)d_in[1];
  const float* emb        = (const float*)d_in[2];
  const float* mw0        = (const float*)d_in[3];
  const float* mw1        = (const float*)d_in[4];
  const float* mw2        = (const float*)d_in[5];
  const float* mb0        = (const float*)d_in[6];
  const float* mb1        = (const float*)d_in[7];
  const float* mb2        = (const float*)d_in[8];
  const float* z_main     = (const float*)d_in[9];
  const float* pw0        = (const float*)d_in[10];
  const float* pw1        = (const float*)d_in[11];
  const float* pw2        = (const float*)d_in[12];
  const float* pb0        = (const float*)d_in[13];
  const float* pb1        = (const float*)d_in[14];
  const float* pb2        = (const float*)d_in[15];
  const float* z_pairs    = (const float*)d_in[16];
  const int*   pairs_list = (const int*)d_in[17];
  const int*   foff       = (const int*)d_in[18];
  float* ws   = (float*)d_ws;
  float* out  = (float*)d_out;
  float* part = ws;
  float* s2   = ws + WS_S2;
  int*   pt   = (int*)(ws + WS_PT);

  transpose_pairs_kernel<<<dim3(16, 126), 256, 0, stream>>>(pairs, pt);
  fused_groups_kernel<<<NG * BPG, 256, 0, stream>>>(
      mains, pt, emb, mw0, mw1, mw2, mb0, mb1, mb2, z_main, pw0, pw1, pw2,
      pb0, pb1, pb2, z_pairs, pairs_list, foff, part);
  reduce1_kernel<<<dim3(2, NSEG), 256, 0, stream>>>(part, s2);
  reduce2_kernel<<<2, 256, 0, stream>>>(s2, out);
}

// Round 4
// 395.822 us; speedup vs baseline: 5.4121x; 5.2654x over previous
//
#include <hip/hip_runtime.h>

// DNAMite GAM on MI355X. Round 3: weights staged in LDS (f16, XOR-swizzled)
// instead of VGPR B-fragments — rounds 1-3 were silently spilling registers
// to scratch (WRITE_SIZE 661 MB) and serializing on the reloads.
// One block per group: weights read from HBM exactly once.

typedef _Float16 f16x8 __attribute__((ext_vector_type(8)));
typedef float f32x4 __attribute__((ext_vector_type(4)));

constexpr int Bsz = 512;
constexpr int NF  = 64;
constexpr int NE  = 32;
constexpr int NH  = 128;
constexpr int NP  = 2016;
constexpr int NG  = NP + NF;       // 2080 groups = grid
constexpr int BT  = 64;            // batch tile
constexpr int NSEG = 8, GSEG = NG / NSEG;  // 260

// ws layout (floats): [NG*Bsz] partials | [NSEG*Bsz] stage2 | pairsT ints
constexpr size_t WS_S2 = (size_t)NG * Bsz;
constexpr size_t WS_PT = WS_S2 + (size_t)NSEG * Bsz;

__device__ __forceinline__ float smoothz(float z) {
  float s = fmaf(-2.0f * z * z, z, fmaf(1.5f, z, 0.5f));
  if (z <= -0.5f) s = 0.0f;
  if (z >=  0.5f) s = 1.0f;
  return s;
}

// Swizzled f16 tile store: element (row, k) -> row*ldk + ((k>>3)^(row&7))*8 + (k&7)
__device__ __forceinline__ void put_sw(_Float16* base, int ldk, int row, int k,
                                       float v) {
  base[row * ldk + (((k >> 3) ^ (row & 7)) * 8) + (k & 7)] = (_Float16)v;
}

// [512][4032] -> [4032][512] int transpose, LDS-tiled 32x32.
__global__ void transpose_pairs_kernel(const int* __restrict__ pairs,
                                       int* __restrict__ pt) {
  __shared__ int tile[32][33];
  const int bt = blockIdx.x;
  const int qt = blockIdx.y;
  const int t  = threadIdx.x;
  const int tq = t & 7, tb = t >> 3;
  const int brow  = bt * 32 + tb;
  const int qbase = qt * 32 + tq * 4;
#pragma unroll
  for (int j = 0; j < 4; ++j)
    tile[tb][tq * 4 + j] = pairs[brow * (2 * NP) + qbase + j];
  __syncthreads();
  const int ob = t & 7, oq = t >> 3;
  const int qrow = qt * 32 + oq;
#pragma unroll
  for (int j = 0; j < 4; ++j)
    pt[(size_t)qrow * Bsz + bt * 32 + ob * 4 + j] = tile[ob * 4 + j][oq];
}

__global__ __launch_bounds__(256, 2) void fused_groups_kernel(
    const int* __restrict__ mains, const int* __restrict__ pt,
    const float* __restrict__ emb,
    const float* __restrict__ mw0, const float* __restrict__ mw1,
    const float* __restrict__ mw2, const float* __restrict__ mb0,
    const float* __restrict__ mb1, const float* __restrict__ mb2,
    const float* __restrict__ z_main,
    const float* __restrict__ pw0, const float* __restrict__ pw1,
    const float* __restrict__ pw2, const float* __restrict__ pb0,
    const float* __restrict__ pb1, const float* __restrict__ pb2,
    const float* __restrict__ z_pairs,
    const int* __restrict__ pairs_list, const int* __restrict__ foff,
    float* __restrict__ ws) {
  // B-matrices in LDS as [col][k], XOR-swizzled 16B blocks (2-way max).
  __shared__ _Float16 sW0[NH * 64];    // 16 KB (pairs use k<64, mains k<32)
  __shared__ _Float16 sW1[NH * NH];    // 32 KB
  __shared__ _Float16 sA[BT * 64];     // 8 KB
  __shared__ _Float16 sH[BT * NH];     // 16 KB
  __shared__ float    sRed[4 * BT];    // 1 KB

  const int t    = threadIdx.x;
  const int wave = t >> 6;
  const int lane = t & 63;
  const int l    = lane & 15;
  const int qd   = lane >> 4;
  const int wnb  = wave * 32;
  const int g    = blockIdx.x;
  const bool is_pair = (g < NP);

  const float *W0, *W1, *w2p, *bv0, *bv1;
  float b2s, z;
  int kc0, off0 = 0, off1 = 0, fid = 0;
  if (is_pair) {
    W0  = pw0 + (size_t)g * (2 * NE * NH);
    W1  = pw1 + (size_t)g * (NH * NH);
    w2p = pw2 + (size_t)g * NH;
    bv0 = pb0 + (size_t)g * NH;
    bv1 = pb1 + (size_t)g * NH;
    b2s = pb2[g];
    z   = smoothz(z_pairs[g]);
    kc0 = 2;
    off0 = foff[pairs_list[2 * g + 0]];
    off1 = foff[pairs_list[2 * g + 1]];
  } else {
    fid = g - NP;
    W0  = mw0 + (size_t)fid * (NE * NH);
    W1  = mw1 + (size_t)fid * (NH * NH);
    w2p = mw2 + (size_t)fid * NH;
    bv0 = mb0 + (size_t)fid * NH;
    bv1 = mb1 + (size_t)fid * NH;
    b2s = mb2[fid];
    z   = smoothz(z_main[fid]);
    kc0 = 1;
    off0 = foff[fid];
  }

  // Per-lane bias / w2 for this lane's two output columns.
  float b0v[2], b1v[2], wv2[2];
#pragma unroll
  for (int nc = 0; nc < 2; ++nc) {
    const int col = wnb + nc * 16 + l;
    b0v[nc] = bv0[col];
    b1v[nc] = bv1[col];
    wv2[nc] = w2p[col];
  }

  // ---- stage weights into LDS (coalesced float4 loads, f16 swizzled) ----
#pragma unroll 2
  for (int i = 0; i < kc0 * 4; ++i) {
    const int f = (t + i * 256) * 4;       // flat idx into W0[k][col]
    const float4 v = *(const float4*)(W0 + f);
    const int k = f >> 7, c = f & 127;
    put_sw(sW0, 64, c + 0, k, v.x);
    put_sw(sW0, 64, c + 1, k, v.y);
    put_sw(sW0, 64, c + 2, k, v.z);
    put_sw(sW0, 64, c + 3, k, v.w);
  }
#pragma unroll 4
  for (int i = 0; i < 16; ++i) {
    const int f = (t + i * 256) * 4;       // flat idx into W1[k][col]
    const float4 v = *(const float4*)(W1 + f);
    const int k = f >> 7, c = f & 127;
    put_sw(sW1, NH, c + 0, k, v.x);
    put_sw(sW1, NH, c + 1, k, v.y);
    put_sw(sW1, NH, c + 2, k, v.z);
    put_sw(sW1, NH, c + 3, k, v.w);
  }

  const int col0 = wnb + l, col1 = wnb + 16 + l;
  const int cs0 = (col0 & 7), cs1 = (col1 & 7);

  for (int tile = 0; tile < Bsz / BT; ++tile) {
    const int bbase = tile * BT;
    __syncthreads();  // weights staged / prior tile fully consumed

    // ---- stage layer-0 input into sA (f16, swizzled) ----
    {
      const int row = t & 63;
      const int q   = t >> 6;
      const int b   = bbase + row;
      if (is_pair) {
        const int which = q >> 1;
        const int bin = pt[(size_t)(2 * g + which) * Bsz + b];  // coalesced
        const int idx = bin + (which ? off1 : off0);
        const float* er = emb + (size_t)idx * NE + (q & 1) * 16;
        const float4 e0 = ((const float4*)er)[0];
        const float4 e1 = ((const float4*)er)[1];
        const float4 e2 = ((const float4*)er)[2];
        const float4 e3 = ((const float4*)er)[3];
        f16x8 h0, h1;
        h0[0] = (_Float16)e0.x; h0[1] = (_Float16)e0.y;
        h0[2] = (_Float16)e0.z; h0[3] = (_Float16)e0.w;
        h0[4] = (_Float16)e1.x; h0[5] = (_Float16)e1.y;
        h0[6] = (_Float16)e1.z; h0[7] = (_Float16)e1.w;
        h1[0] = (_Float16)e2.x; h1[1] = (_Float16)e2.y;
        h1[2] = (_Float16)e2.z; h1[3] = (_Float16)e2.w;
        h1[4] = (_Float16)e3.x; h1[5] = (_Float16)e3.y;
        h1[6] = (_Float16)e3.z; h1[7] = (_Float16)e3.w;
        const int blk0 = (2 * q)     ^ (row & 7);
        const int blk1 = (2 * q + 1) ^ (row & 7);
        *(f16x8*)&sA[row * 64 + blk0 * 8] = h0;
        *(f16x8*)&sA[row * 64 + blk1 * 8] = h1;
      } else {
        const int bin = mains[b * NF + fid];
        const int idx = bin + off0;
        const float* er = emb + (size_t)idx * NE + q * 8;
        const float4 e0 = ((const float4*)er)[0];
        const float4 e1 = ((const float4*)er)[1];
        f16x8 h0;
        h0[0] = (_Float16)e0.x; h0[1] = (_Float16)e0.y;
        h0[2] = (_Float16)e0.z; h0[3] = (_Float16)e0.w;
        h0[4] = (_Float16)e1.x; h0[5] = (_Float16)e1.y;
        h0[6] = (_Float16)e1.z; h0[7] = (_Float16)e1.w;
        const int blk = q ^ (row & 7);
        *(f16x8*)&sA[row * 64 + blk * 8] = h0;
      }
    }
    __syncthreads();

    // ---- GEMM0: H1 = relu(E*W0 + b0), B from LDS ----
    f32x4 acc0[4][2];
#pragma unroll
    for (int m = 0; m < 4; ++m)
#pragma unroll
      for (int nc = 0; nc < 2; ++nc)
        acc0[m][nc] = (f32x4){b0v[nc], b0v[nc], b0v[nc], b0v[nc]};

    for (int kc = 0; kc < kc0; ++kc) {
      const int kb = kc * 4 + qd;
      const f16x8 bf0 = *(const f16x8*)&sW0[col0 * 64 + ((kb ^ cs0) * 8)];
      const f16x8 bf1 = *(const f16x8*)&sW0[col1 * 64 + ((kb ^ cs1) * 8)];
#pragma unroll
      for (int m = 0; m < 4; ++m) {
        const int brow = m * 16 + l;
        const f16x8 af = *(const f16x8*)&sA[brow * 64 + ((kb ^ (brow & 7)) * 8)];
        acc0[m][0] = __builtin_amdgcn_mfma_f32_16x16x32_f16(af, bf0, acc0[m][0], 0, 0, 0);
        acc0[m][1] = __builtin_amdgcn_mfma_f32_16x16x32_f16(af, bf1, acc0[m][1], 0, 0, 0);
      }
    }

    // ---- relu + write H1 to sH (f16, swizzled); D: row=qd*4+r, col=l ----
#pragma unroll
    for (int m = 0; m < 4; ++m)
#pragma unroll
      for (int nc = 0; nc < 2; ++nc)
#pragma unroll
        for (int r = 0; r < 4; ++r) {
          const float v = fmaxf(acc0[m][nc][r], 0.0f);
          const int row = m * 16 + qd * 4 + r;
          const int col = wnb + nc * 16 + l;
          sH[row * NH + (((col >> 3) ^ (row & 7)) * 8) + (col & 7)] =
              (_Float16)v;
        }
    __syncthreads();

    // ---- GEMM1: H2 = relu(H1*W1 + b1), B from LDS ----
    f32x4 acc1[4][2];
#pragma unroll
    for (int m = 0; m < 4; ++m)
#pragma unroll
      for (int nc = 0; nc < 2; ++nc)
        acc1[m][nc] = (f32x4){b1v[nc], b1v[nc], b1v[nc], b1v[nc]};

#pragma unroll
    for (int kc = 0; kc < 4; ++kc) {
      const int kb = kc * 4 + qd;
      const f16x8 bf0 = *(const f16x8*)&sW1[col0 * NH + ((kb ^ cs0) * 8)];
      const f16x8 bf1 = *(const f16x8*)&sW1[col1 * NH + ((kb ^ cs1) * 8)];
#pragma unroll
      for (int m = 0; m < 4; ++m) {
        const int brow = m * 16 + l;
        const f16x8 af = *(const f16x8*)&sH[brow * NH + ((kb ^ (brow & 7)) * 8)];
        acc1[m][0] = __builtin_amdgcn_mfma_f32_16x16x32_f16(af, bf0, acc1[m][0], 0, 0, 0);
        acc1[m][1] = __builtin_amdgcn_mfma_f32_16x16x32_f16(af, bf1, acc1[m][1], 0, 0, 0);
      }
    }

    // ---- layer 2: per-wave partial y over its 32 cols ----
    float v16[16];
#pragma unroll
    for (int m = 0; m < 4; ++m)
#pragma unroll
      for (int r = 0; r < 4; ++r)
        v16[m * 4 + r] = fmaf(fmaxf(acc1[m][0][r], 0.0f), wv2[0],
                              fmaxf(acc1[m][1][r], 0.0f) * wv2[1]);

    const int lb0 = l & 1, lb1 = (l >> 1) & 1, lb2 = (l >> 2) & 1,
              lb3 = (l >> 3) & 1;
    float v8[8];
#pragma unroll
    for (int i = 0; i < 8; ++i) {
      const float mine   = lb0 ? v16[2 * i + 1] : v16[2 * i];
      const float theirs = lb0 ? v16[2 * i]     : v16[2 * i + 1];
      v8[i] = mine + __shfl_xor(theirs, 1, 64);
    }
    float v4[4];
#pragma unroll
    for (int i = 0; i < 4; ++i) {
      const float mine   = lb1 ? v8[2 * i + 1] : v8[2 * i];
      const float theirs = lb1 ? v8[2 * i]     : v8[2 * i + 1];
      v4[i] = mine + __shfl_xor(theirs, 2, 64);
    }
    float v2[2];
#pragma unroll
    for (int i = 0; i < 2; ++i) {
      const float mine   = lb2 ? v4[2 * i + 1] : v4[2 * i];
      const float theirs = lb2 ? v4[2 * i]     : v4[2 * i + 1];
      v2[i] = mine + __shfl_xor(theirs, 4, 64);
    }
    const float mine1   = lb3 ? v2[1] : v2[0];
    const float theirs1 = lb3 ? v2[0] : v2[1];
    const float v1 = mine1 + __shfl_xor(theirs1, 8, 64);

    // cross-wave reduce through LDS, ONE write per (g, b) — no atomics
    const int row_local = (l >> 2) * 16 + qd * 4 + (l & 3);
    sRed[wave * BT + row_local] = v1;
    __syncthreads();
    if (t < BT) {
      const float s =
          sRed[t] + sRed[BT + t] + sRed[2 * BT + t] + sRed[3 * BT + t];
      ws[(size_t)g * Bsz + bbase + t] = (s + b2s) * z;
    }
  }
}

__global__ void reduce1_kernel(const float* __restrict__ part,
                               float* __restrict__ s2) {
  const int b   = blockIdx.x * 256 + threadIdx.x;
  const int seg = blockIdx.y;
  float s = 0.0f;
#pragma unroll 8
  for (int g = seg * GSEG; g < (seg + 1) * GSEG; ++g)
    s += part[(size_t)g * Bsz + b];
  s2[seg * Bsz + b] = s;
}

__global__ void reduce2_kernel(const float* __restrict__ s2,
                               float* __restrict__ out) {
  const int b = blockIdx.x * 256 + threadIdx.x;
  float s = 0.0f;
#pragma unroll
  for (int k = 0; k < NSEG; ++k) s += s2[k * Bsz + b];
  out[b] = s;
}

extern "C" void kernel_launch(void* const* d_in, const int* in_sizes, int n_in,
                              void* d_out, int out_size, void* d_ws,
                              size_t ws_size, hipStream_t stream) {
  const int*   mains      = (const int*)d_in[0];
  const int*   pairs      = (const int*)d_in[1];
  const float* emb        = (const float*)d_in[2];
  const float* mw0        = (const float*)d_in[3];
  const float* mw1        = (const float*)d_in[4];
  const float* mw2        = (const float*)d_in[5];
  const float* mb0        = (const float*)d_in[6];
  const float* mb1        = (const float*)d_in[7];
  const float* mb2        = (const float*)d_in[8];
  const float* z_main     = (const float*)d_in[9];
  const float* pw0        = (const float*)d_in[10];
  const float* pw1        = (const float*)d_in[11];
  const float* pw2        = (const float*)d_in[12];
  const float* pb0        = (const float*)d_in[13];
  const float* pb1        = (const float*)d_in[14];
  const float* pb2        = (const float*)d_in[15];
  const float* z_pairs    = (const float*)d_in[16];
  const int*   pairs_list = (const int*)d_in[17];
  const int*   foff       = (const int*)d_in[18];
  float* ws   = (float*)d_ws;
  float* out  = (float*)d_out;
  float* part = ws;
  float* s2   = ws + WS_S2;
  int*   pt   = (int*)(ws + WS_PT);

  transpose_pairs_kernel<<<dim3(16, 126), 256, 0, stream>>>(pairs, pt);
  fused_groups_kernel<<<NG, 256, 0, stream>>>(
      mains, pt, emb, mw0, mw1, mw2, mb0, mb1, mb2, z_main, pw0, pw1, pw2,
      pb0, pb1, pb2, z_pairs, pairs_list, foff, part);
  reduce1_kernel<<<dim3(2, NSEG), 256, 0, stream>>>(part, s2);
  reduce2_kernel<<<2, 256, 0, stream>>>(s2, out);
}